// Round 4
// baseline (202.301 us; speedup 1.0000x reference)
//
#include <hip/hip_runtime.h>
#include <hip/hip_bf16.h>

#define KDIM 1024
#define NDIM 1024
#define NEXP 8
#define TTOK 8192

typedef __bf16 bf16x8 __attribute__((ext_vector_type(8)));
typedef __bf16 bf16x4 __attribute__((ext_vector_type(4)));
typedef float  f32x4  __attribute__((ext_vector_type(4)));

// ---------------- prepass: x fp32->bf16, W fp32 [K][N] -> Wt bf16 [N][K] ----------------
__global__ __launch_bounds__(256) void prepass(
    const float* __restrict__ x, const float* __restrict__ W,
    __bf16* __restrict__ xb, __bf16* __restrict__ Wt)
{
  __shared__ __align__(16) __bf16 Lt[64 * 72];   // [n][k], stride 72 (144B, 16B-aligned)
  const int t = threadIdx.x;
  if (blockIdx.x < 1024) {
    int gid = blockIdx.x * 256 + t;
#pragma unroll
    for (int p = 0; p < 4; ++p) {
      size_t i8 = (size_t)(gid + p * 262144) * 8;
      float4 a = *(const float4*)(x + i8);
      float4 b = *(const float4*)(x + i8 + 4);
      bf16x8 v;
      v[0] = (__bf16)a.x; v[1] = (__bf16)a.y; v[2] = (__bf16)a.z; v[3] = (__bf16)a.w;
      v[4] = (__bf16)b.x; v[5] = (__bf16)b.y; v[6] = (__bf16)b.z; v[7] = (__bf16)b.w;
      *(bf16x8*)(xb + i8) = v;
    }
  } else {
    int bid = blockIdx.x - 1024;
    int e = bid >> 8, r = bid & 255;
    int k0 = (r >> 4) * 64, n0 = (r & 15) * 64;
    const float* Wp = W + (size_t)e * KDIM * NDIM;
    int rr0 = t >> 4, c4 = t & 15;
#pragma unroll
    for (int p = 0; p < 4; ++p) {
      int kk = rr0 + p * 16;
      float4 v = *(const float4*)(Wp + (size_t)(k0 + kk) * NDIM + n0 + c4 * 4);
      Lt[(c4 * 4 + 0) * 72 + kk] = (__bf16)v.x;
      Lt[(c4 * 4 + 1) * 72 + kk] = (__bf16)v.y;
      Lt[(c4 * 4 + 2) * 72 + kk] = (__bf16)v.z;
      Lt[(c4 * 4 + 3) * 72 + kk] = (__bf16)v.w;
    }
    __syncthreads();
    __bf16* Wte = Wt + (size_t)e * NDIM * KDIM;
    int n = t >> 2, kq = t & 3;
#pragma unroll
    for (int q = 0; q < 2; ++q) {
      int kqq = kq + q * 4;
      bf16x8 v = *(const bf16x8*)(Lt + n * 72 + kqq * 8);
      *(bf16x8*)(Wte + (size_t)(n0 + n) * KDIM + k0 + kqq * 8) = v;
    }
  }
}

// ---------------- main GEMM: zero-LDS, zero-barrier, direct fragment loads ----------------
// Each wave owns a 64x64 quadrant of the block's 128x128 tile. Both xb [M][K]
// and Wt [N][K] are K-contiguous, so a lane's MFMA fragment (8 bf16) is one
// native 16B global load. No __syncthreads anywhere in the K-loop -> compiler
// emits fine-grained per-use vmcnt(N); 4-deep register pipeline gives a
// load->use distance of 3 MFMA groups (~240+ cycles).
__global__ __launch_bounds__(256) void moe_gemm_direct(
    const __bf16* __restrict__ xb, const __bf16* __restrict__ Wt,
    const int* __restrict__ gs, const float* __restrict__ bias,
    float* __restrict__ out)
{
  // decode flat m-tile id -> (expert, row0, rows)
  int y = blockIdx.y;
  int e = 0, row0 = 0, rows = 0, found = 0, off = 0;
#pragma unroll
  for (int i = 0; i < NEXP; ++i) {
    int g = gs[i];
    int tc = (g + 127) >> 7;
    if (!found) {
      if (y < tc) { found = 1; e = i; row0 = off + y * 128; rows = min(128, g - y * 128); }
      else y -= tc;
    }
    off += g;
  }
  if (!found) return;
  const int n0 = blockIdx.x * 128;

  const int t = threadIdx.x, lane = t & 63, wv = t >> 6;
  const int wm = wv & 1, wn = wv >> 1, lm = lane & 15, lg = lane >> 4;

  // Fragment bases. A rows >= `rows` read past the group (worst case ~254KB past
  // xb end, which lands inside Wt -> in-bounds of d_ws, finite garbage); those
  // C rows are never stored. K offsets stay in [0,1024).
  const __bf16* aB = xb + (size_t)(row0 + wm * 64 + lm) * KDIM + lg * 8;
  const __bf16* bB = Wt + (size_t)e * NDIM * KDIM + (size_t)(n0 + wn * 64 + lm) * KDIM + lg * 8;

  f32x4 acc[4][4] = {};
  bf16x8 aF[4][4], bF[4][4];   // 4-deep pipeline x 4 fragments

  auto ld = [&](int kt, bf16x8* a, bf16x8* b) {
    const __bf16* ap = aB + kt * 32;
    const __bf16* bp = bB + kt * 32;
#pragma unroll
    for (int i = 0; i < 4; ++i) a[i] = *(const bf16x8*)(ap + (size_t)(i * 16) * KDIM);
#pragma unroll
    for (int j = 0; j < 4; ++j) b[j] = *(const bf16x8*)(bp + (size_t)(j * 16) * KDIM);
  };
  auto mm = [&](bf16x8* a, bf16x8* b) {
#pragma unroll
    for (int i = 0; i < 4; ++i)
#pragma unroll
      for (int j = 0; j < 4; ++j)
        acc[i][j] = __builtin_amdgcn_mfma_f32_16x16x32_bf16(a[i], b[j], acc[i][j], 0, 0, 0);
  };

  ld(0, aF[0], bF[0]);
  ld(1, aF[1], bF[1]);
  ld(2, aF[2], bF[2]);
#pragma unroll 1
  for (int kt = 0; kt < KDIM / 32; kt += 4) {
    if (kt + 3 < 32) ld(kt + 3, aF[3], bF[3]);
    mm(aF[0], bF[0]);
    if (kt + 4 < 32) ld(kt + 4, aF[0], bF[0]);
    mm(aF[1], bF[1]);
    if (kt + 5 < 32) ld(kt + 5, aF[1], bF[1]);
    mm(aF[2], bF[2]);
    if (kt + 6 < 32) ld(kt + 6, aF[2], bF[2]);
    mm(aF[3], bF[3]);
  }

  float bj[4];
#pragma unroll
  for (int j = 0; j < 4; ++j) bj[j] = bias[e * NDIM + n0 + wn * 64 + j * 16 + lm];
  float* op = out + (size_t)row0 * NDIM + n0;
#pragma unroll
  for (int i = 0; i < 4; ++i)
#pragma unroll
    for (int r = 0; r < 4; ++r) {
      int rr = wm * 64 + i * 16 + lg * 4 + r;   // C/D: row = quad*4 + reg, col = lane&15
      if (rr < rows) {
#pragma unroll
        for (int j = 0; j < 4; ++j)
          op[(size_t)rr * NDIM + wn * 64 + j * 16 + lm] = acc[i][j][r] + bj[j];
      }
    }
}

// ---------------- round-1 fallback (fp32 in-loop conversion) for small ws ----------------
#define LDA 40
__global__ __launch_bounds__(256) void moe_gemm_kernel(
    const float* __restrict__ x, const int* __restrict__ gs,
    const float* __restrict__ W, const float* __restrict__ bias,
    float* __restrict__ out)
{
  __shared__ __bf16 Al[128 * LDA];
  __shared__ __bf16 Bl[128 * LDA];
  const int e = blockIdx.z, mt = blockIdx.y, nt = blockIdx.x;
  int off = 0;
#pragma unroll
  for (int i = 0; i < NEXP; ++i) { int g = gs[i]; if (i < e) off += g; }
  const int ge = gs[e];
  const int m0 = mt * 128;
  if (m0 >= ge) return;
  const int rows = min(128, ge - m0);
  const int row0 = off + m0;
  const int n0 = nt * 128;
  const int t = threadIdx.x, lane = t & 63, wv = t >> 6;
  const int wm = wv & 1, wn = wv >> 1, lm = lane & 15, lg = lane >> 4;
  const int am = t >> 3, kq = t & 7, nb = t & 127, kh = t >> 7;
  float4 aReg[4]; float bReg[16];
  const float* Wp = W + (size_t)e * KDIM * NDIM + n0 + nb;
  auto load_tile = [&](int kt) {
#pragma unroll
    for (int p = 0; p < 4; ++p) {
      int r = am + 32 * p;
      if (r < rows) aReg[p] = *(const float4*)(x + (size_t)(row0 + r) * KDIM + kt * 32 + kq * 4);
      else aReg[p] = make_float4(0.f, 0.f, 0.f, 0.f);
    }
    const float* wp = Wp + (size_t)(kt * 32 + kh * 16) * NDIM;
#pragma unroll
    for (int j = 0; j < 16; ++j) bReg[j] = wp[(size_t)j * NDIM];
  };
  auto store_tile = [&]() {
#pragma unroll
    for (int p = 0; p < 4; ++p) {
      bf16x4 v;
      v[0] = (__bf16)aReg[p].x; v[1] = (__bf16)aReg[p].y;
      v[2] = (__bf16)aReg[p].z; v[3] = (__bf16)aReg[p].w;
      *(bf16x4*)(Al + (am + 32 * p) * LDA + kq * 4) = v;
    }
    bf16x8 b0, b1;
#pragma unroll
    for (int j = 0; j < 8; ++j) { b0[j] = (__bf16)bReg[j]; b1[j] = (__bf16)bReg[8 + j]; }
    *(bf16x8*)(Bl + nb * LDA + kh * 16) = b0;
    *(bf16x8*)(Bl + nb * LDA + kh * 16 + 8) = b1;
  };
  f32x4 acc[4][4] = {};
  load_tile(0);
#pragma unroll 1
  for (int kt = 0; kt < KDIM / 32; ++kt) {
    __syncthreads();
    store_tile();
    __syncthreads();
    if (kt + 1 < KDIM / 32) load_tile(kt + 1);
    bf16x8 af[4], bfr[4];
#pragma unroll
    for (int i = 0; i < 4; ++i)
      af[i] = *(const bf16x8*)(Al + (wm * 64 + i * 16 + lm) * LDA + lg * 8);
#pragma unroll
    for (int j = 0; j < 4; ++j)
      bfr[j] = *(const bf16x8*)(Bl + (wn * 64 + j * 16 + lm) * LDA + lg * 8);
#pragma unroll
    for (int i = 0; i < 4; ++i)
#pragma unroll
      for (int j = 0; j < 4; ++j)
        acc[i][j] = __builtin_amdgcn_mfma_f32_16x16x32_bf16(af[i], bfr[j], acc[i][j], 0, 0, 0);
  }
  float bj[4];
#pragma unroll
  for (int j = 0; j < 4; ++j) bj[j] = bias[e * NDIM + n0 + wn * 64 + j * 16 + lm];
  float* op = out + (size_t)row0 * NDIM + n0;
#pragma unroll
  for (int i = 0; i < 4; ++i)
#pragma unroll
    for (int r = 0; r < 4; ++r) {
      int rr = wm * 64 + i * 16 + lg * 4 + r;
      if (rr < rows) {
#pragma unroll
        for (int j = 0; j < 4; ++j)
          op[(size_t)rr * NDIM + wn * 64 + j * 16 + lm] = acc[i][j][r] + bj[j];
      }
    }
}

extern "C" void kernel_launch(void* const* d_in, const int* in_sizes, int n_in,
                              void* d_out, int out_size, void* d_ws, size_t ws_size,
                              hipStream_t stream) {
  const float* x    = (const float*)d_in[0];
  const int*   gs   = (const int*)d_in[1];
  const float* W    = (const float*)d_in[2];
  const float* bias = (const float*)d_in[3];
  float*       out  = (float*)d_out;

  const size_t xb_bytes = (size_t)TTOK * KDIM * 2;
  const size_t wt_bytes = (size_t)NEXP * KDIM * NDIM * 2;
  if (ws_size >= xb_bytes + wt_bytes) {
    __bf16* xb = (__bf16*)d_ws;
    __bf16* Wt = (__bf16*)((char*)d_ws + xb_bytes);
    prepass<<<dim3(1024 + 2048), 256, 0, stream>>>(x, W, xb, Wt);
    moe_gemm_direct<<<dim3(NDIM / 128, 72), 256, 0, stream>>>(xb, Wt, gs, bias, out);
  } else {
    moe_gemm_kernel<<<dim3(NDIM / 128, TTOK / 128, NEXP), 256, 0, stream>>>(x, gs, W, bias, out);
  }
}

// Round 5
// 144.437 us; speedup vs baseline: 1.4006x; 1.4006x over previous
//
#include <hip/hip_runtime.h>
#include <hip/hip_bf16.h>

#define KDIM 1024
#define NDIM 1024
#define NEXP 8
#define TTOK 8192

typedef __bf16 bf16x8 __attribute__((ext_vector_type(8)));
typedef __bf16 bf16x4 __attribute__((ext_vector_type(4)));
typedef float  f32x4  __attribute__((ext_vector_type(4)));

// Fragment-swizzled layouts (16B per lane-slot):
//   swA slot(panel,kt,lane) = x[panel*16 + (lane&15)][kt*32 + (lane>>4)*8 .. +8]
//   swB slot(e,panel,kt,lane) = W[e][kt*32 + (lane>>4)*8 .. +8][panel*16 + (lane&15)]
// -> a wave's MFMA fragment load is base + lane*16: one coalesced 1KiB transaction.

// ---------------- prepass: build swA (x fp32->bf16) and swB (W transpose) ----------------
__global__ __launch_bounds__(256) void prepass(
    const float* __restrict__ x, const float* __restrict__ W,
    __bf16* __restrict__ swA, __bf16* __restrict__ swB)
{
  __shared__ __align__(16) __bf16 Lt[64 * 72];   // [n][k], stride 72 elems (144B = 9*16, aligned)
  const int t = threadIdx.x;
  if (blockIdx.x < 1024) {
    // x part: 512 panels x 32 kt x 64 lanes = 1M slots; 1024 blocks x 256 thr x 4
#pragma unroll
    for (int p = 0; p < 4; ++p) {
      int s = blockIdx.x * 1024 + p * 256 + t;
      int lane = s & 63, kt = (s >> 6) & 31, panel = s >> 11;
      int row = panel * 16 + (lane & 15);
      int k0 = kt * 32 + ((lane >> 4) << 3);
      const float* xp = x + (size_t)row * KDIM + k0;
      float4 a = *(const float4*)xp;
      float4 b = *(const float4*)(xp + 4);
      bf16x8 v;
      v[0] = (__bf16)a.x; v[1] = (__bf16)a.y; v[2] = (__bf16)a.z; v[3] = (__bf16)a.w;
      v[4] = (__bf16)b.x; v[5] = (__bf16)b.y; v[6] = (__bf16)b.z; v[7] = (__bf16)b.w;
      *(bf16x8*)(swA + (size_t)s * 8) = v;       // consecutive t -> contiguous 16B: coalesced
    }
  } else {
    // W part: per 64x64 tile, transpose via LDS then write fragment-ordered
    int bid = blockIdx.x - 1024;                 // 2048 blocks: 8 experts x 16 k0 x 16 n0
    int e = bid >> 8, r = bid & 255;
    int k0 = (r >> 4) * 64, n0 = (r & 15) * 64;
    const float* Wp = W + (size_t)e * KDIM * NDIM;
    int rr0 = t >> 4, c4 = t & 15;
#pragma unroll
    for (int p = 0; p < 4; ++p) {
      int kk = rr0 + p * 16;
      float4 v = *(const float4*)(Wp + (size_t)(k0 + kk) * NDIM + n0 + c4 * 4);
      Lt[(c4 * 4 + 0) * 72 + kk] = (__bf16)v.x;
      Lt[(c4 * 4 + 1) * 72 + kk] = (__bf16)v.y;
      Lt[(c4 * 4 + 2) * 72 + kk] = (__bf16)v.z;
      Lt[(c4 * 4 + 3) * 72 + kk] = (__bf16)v.w;
    }
    __syncthreads();
    // 64x64 tile = 4 n-panels x 2 kts x 64 lanes = 512 slots; 256 thr x 2
#pragma unroll
    for (int q = 0; q < 2; ++q) {
      int slot = q * 256 + t;
      int lane = slot & 63, grp = slot >> 6;     // grp 0..7
      int np = grp & 3, kt2 = grp >> 2;
      int nl = np * 16 + (lane & 15);
      int kl = kt2 * 32 + ((lane >> 4) << 3);
      bf16x8 v = *(const bf16x8*)(Lt + nl * 72 + kl);
      int panel = (n0 >> 4) + np;
      int ktg = (k0 >> 5) + kt2;
      size_t sg = (((size_t)e * 64 + panel) * 32 + ktg) * 64 + lane;
      *(bf16x8*)(swB + sg * 8) = v;              // coalesced 1KiB per wave
    }
  }
}

// ---------------- GEMM: zero-LDS, zero-barrier, coalesced fragment loads ----------------
// m-tiles on the ABSOLUTE 128-row grid; boundary tiles straddling two experts get
// one block per overlapping expert; stores guarded to [lo,hi).
__global__ __launch_bounds__(256, 2) void moe_gemm_frag(
    const __bf16* __restrict__ swA, const __bf16* __restrict__ swB,
    const int* __restrict__ gs, const float* __restrict__ bias,
    float* __restrict__ out)
{
  int y = blockIdx.y;
  int e = 0, tile0 = 0, lo = 0, hi = 0, found = 0, off = 0;
#pragma unroll
  for (int i = 0; i < NEXP; ++i) {
    int g = gs[i];
    int first = off >> 7;
    int cnt = (g > 0) ? (((off + g - 1) >> 7) - first + 1) : 0;
    if (!found) {
      if (y < cnt) {
        found = 1; e = i; tile0 = (first + y) << 7;
        lo = max(tile0, off); hi = min(tile0 + 128, off + g);
      } else y -= cnt;
    }
    off += g;
  }
  if (!found) return;
  const int n0 = blockIdx.x * 128;

  const int t = threadIdx.x, lane = t & 63, wv = t >> 6;
  const int wm = wv & 1, wn = wv >> 1, lm = lane & 15, lg = lane >> 4;

  // fragment bases: frag i is +i*16384 elems (panel stride 32*64*8), kt is +kt*512
  const __bf16* aB = swA + (((size_t)((tile0 >> 4) + wm * 4) * 32) * 64 + lane) * 8;
  const __bf16* bB = swB + ((((size_t)e * 64 + (n0 >> 4) + wn * 4) * 32) * 64 + lane) * 8;

  f32x4 acc[4][4] = {};
  bf16x8 aF0[4], bF0[4], aF1[4], bF1[4];

  auto ld = [&](int kt, bf16x8* a, bf16x8* b) {
#pragma unroll
    for (int i = 0; i < 4; ++i) a[i] = *(const bf16x8*)(aB + (size_t)i * 16384 + kt * 512);
#pragma unroll
    for (int j = 0; j < 4; ++j) b[j] = *(const bf16x8*)(bB + (size_t)j * 16384 + kt * 512);
  };
  auto mm = [&](bf16x8* a, bf16x8* b) {
#pragma unroll
    for (int i = 0; i < 4; ++i)
#pragma unroll
      for (int j = 0; j < 4; ++j)
        acc[i][j] = __builtin_amdgcn_mfma_f32_16x16x32_bf16(a[i], b[j], acc[i][j], 0, 0, 0);
  };

  ld(0, aF0, bF0);
  ld(1, aF1, bF1);
#pragma unroll 1
  for (int kt = 0; kt < KDIM / 32; kt += 2) {
    mm(aF0, bF0);
    if (kt + 2 < 32) ld(kt + 2, aF0, bF0);   // in flight across next mm: ~1.5-iter distance
    mm(aF1, bF1);
    if (kt + 3 < 32) ld(kt + 3, aF1, bF1);
  }

  float bj[4];
#pragma unroll
  for (int j = 0; j < 4; ++j) bj[j] = bias[e * NDIM + n0 + wn * 64 + j * 16 + lm];
#pragma unroll
  for (int i = 0; i < 4; ++i)
#pragma unroll
    for (int r = 0; r < 4; ++r) {
      int rabs = tile0 + wm * 64 + i * 16 + lg * 4 + r;   // C/D: row = quad*4 + reg
      if (rabs >= lo && rabs < hi) {
#pragma unroll
        for (int j = 0; j < 4; ++j)
          out[(size_t)rabs * NDIM + n0 + wn * 64 + j * 16 + lm] = acc[i][j][r] + bj[j];
      }
    }
}

// ---------------- round-1 fallback (fp32 in-loop conversion) for small ws ----------------
#define LDA 40
__global__ __launch_bounds__(256) void moe_gemm_kernel(
    const float* __restrict__ x, const int* __restrict__ gs,
    const float* __restrict__ W, const float* __restrict__ bias,
    float* __restrict__ out)
{
  __shared__ __bf16 Al[128 * LDA];
  __shared__ __bf16 Bl[128 * LDA];
  const int e = blockIdx.z, mt = blockIdx.y, nt = blockIdx.x;
  int off = 0;
#pragma unroll
  for (int i = 0; i < NEXP; ++i) { int g = gs[i]; if (i < e) off += g; }
  const int ge = gs[e];
  const int m0 = mt * 128;
  if (m0 >= ge) return;
  const int rows = min(128, ge - m0);
  const int row0 = off + m0;
  const int n0 = nt * 128;
  const int t = threadIdx.x, lane = t & 63, wv = t >> 6;
  const int wm = wv & 1, wn = wv >> 1, lm = lane & 15, lg = lane >> 4;
  const int am = t >> 3, kq = t & 7, nb = t & 127, kh = t >> 7;
  float4 aReg[4]; float bReg[16];
  const float* Wp = W + (size_t)e * KDIM * NDIM + n0 + nb;
  auto load_tile = [&](int kt) {
#pragma unroll
    for (int p = 0; p < 4; ++p) {
      int r = am + 32 * p;
      if (r < rows) aReg[p] = *(const float4*)(x + (size_t)(row0 + r) * KDIM + kt * 32 + kq * 4);
      else aReg[p] = make_float4(0.f, 0.f, 0.f, 0.f);
    }
    const float* wp = Wp + (size_t)(kt * 32 + kh * 16) * NDIM;
#pragma unroll
    for (int j = 0; j < 16; ++j) bReg[j] = wp[(size_t)j * NDIM];
  };
  auto store_tile = [&]() {
#pragma unroll
    for (int p = 0; p < 4; ++p) {
      bf16x4 v;
      v[0] = (__bf16)aReg[p].x; v[1] = (__bf16)aReg[p].y;
      v[2] = (__bf16)aReg[p].z; v[3] = (__bf16)aReg[p].w;
      *(bf16x4*)(Al + (am + 32 * p) * LDA + kq * 4) = v;
    }
    bf16x8 b0, b1;
#pragma unroll
    for (int j = 0; j < 8; ++j) { b0[j] = (__bf16)bReg[j]; b1[j] = (__bf16)bReg[8 + j]; }
    *(bf16x8*)(Bl + nb * LDA + kh * 16) = b0;
    *(bf16x8*)(Bl + nb * LDA + kh * 16 + 8) = b1;
  };
  f32x4 acc[4][4] = {};
  load_tile(0);
#pragma unroll 1
  for (int kt = 0; kt < KDIM / 32; ++kt) {
    __syncthreads();
    store_tile();
    __syncthreads();
    if (kt + 1 < KDIM / 32) load_tile(kt + 1);
    bf16x8 af[4], bfr[4];
#pragma unroll
    for (int i = 0; i < 4; ++i)
      af[i] = *(const bf16x8*)(Al + (wm * 64 + i * 16 + lm) * LDA + lg * 8);
#pragma unroll
    for (int j = 0; j < 4; ++j)
      bfr[j] = *(const bf16x8*)(Bl + (wn * 64 + j * 16 + lm) * LDA + lg * 8);
#pragma unroll
    for (int i = 0; i < 4; ++i)
#pragma unroll
      for (int j = 0; j < 4; ++j)
        acc[i][j] = __builtin_amdgcn_mfma_f32_16x16x32_bf16(af[i], bfr[j], acc[i][j], 0, 0, 0);
  }
  float bj[4];
#pragma unroll
  for (int j = 0; j < 4; ++j) bj[j] = bias[e * NDIM + n0 + wn * 64 + j * 16 + lm];
  float* op = out + (size_t)row0 * NDIM + n0;
#pragma unroll
  for (int i = 0; i < 4; ++i)
#pragma unroll
    for (int r = 0; r < 4; ++r) {
      int rr = wm * 64 + i * 16 + lg * 4 + r;
      if (rr < rows) {
#pragma unroll
        for (int j = 0; j < 4; ++j)
          out[(size_t)(row0 + rr) * NDIM + n0 + wn * 64 + j * 16 + lm] = acc[i][j][r] + bj[j];
      }
    }
}

extern "C" void kernel_launch(void* const* d_in, const int* in_sizes, int n_in,
                              void* d_out, int out_size, void* d_ws, size_t ws_size,
                              hipStream_t stream) {
  const float* x    = (const float*)d_in[0];
  const int*   gs   = (const int*)d_in[1];
  const float* W    = (const float*)d_in[2];
  const float* bias = (const float*)d_in[3];
  float*       out  = (float*)d_out;

  const size_t swA_bytes = (size_t)TTOK * KDIM * 2;
  const size_t swB_bytes = (size_t)NEXP * KDIM * NDIM * 2;
  if (ws_size >= swA_bytes + swB_bytes) {
    __bf16* swA = (__bf16*)d_ws;
    __bf16* swB = (__bf16*)((char*)d_ws + swA_bytes);
    prepass<<<dim3(1024 + 2048), 256, 0, stream>>>(x, W, swA, swB);
    // y: absolute 128-row m-tiles overlapped per expert (<=71) ; x: 8 n-tiles
    moe_gemm_frag<<<dim3(NDIM / 128, 72), 256, 0, stream>>>(swA, swB, gs, bias, out);
  } else {
    moe_gemm_kernel<<<dim3(NDIM / 128, TTOK / 128, NEXP), 256, 0, stream>>>(x, gs, W, bias, out);
  }
}

// Round 6
// 143.198 us; speedup vs baseline: 1.4127x; 1.0087x over previous
//
#include <hip/hip_runtime.h>
#include <hip/hip_bf16.h>

#define KDIM 1024
#define NDIM 1024
#define NEXP 8
#define TTOK 8192

typedef __bf16 bf16x8 __attribute__((ext_vector_type(8)));
typedef __bf16 bf16x4 __attribute__((ext_vector_type(4)));
typedef float  f32x4  __attribute__((ext_vector_type(4)));

// Fragment-swizzled layouts (16B per lane-slot):
//   swA slot(panel,kt,lane) = x[panel*16 + (lane&15)][kt*32 + (lane>>4)*8 .. +8]
//   swB slot(e,panel,kt,lane) = W[e][kt*32 + (lane>>4)*8 .. +8][panel*16 + (lane&15)]
// -> a wave's MFMA fragment load is base + lane*16: one coalesced 1KiB transaction.

// ---------------- prepass: build swA (x fp32->bf16) and swB (W transpose) ----------------
__global__ __launch_bounds__(256) void prepass(
    const float* __restrict__ x, const float* __restrict__ W,
    __bf16* __restrict__ swA, __bf16* __restrict__ swB)
{
  __shared__ __align__(16) __bf16 Lt[64 * 72];   // [n][k], stride 72 elems (144B = 9*16, aligned)
  const int t = threadIdx.x;
  if (blockIdx.x < 1024) {
    // x part: 512 panels x 32 kt x 64 lanes = 1M slots; 1024 blocks x 256 thr x 4
#pragma unroll
    for (int p = 0; p < 4; ++p) {
      int s = blockIdx.x * 1024 + p * 256 + t;
      int lane = s & 63, kt = (s >> 6) & 31, panel = s >> 11;
      int row = panel * 16 + (lane & 15);
      int k0 = kt * 32 + ((lane >> 4) << 3);
      const float* xp = x + (size_t)row * KDIM + k0;
      float4 a = *(const float4*)xp;
      float4 b = *(const float4*)(xp + 4);
      bf16x8 v;
      v[0] = (__bf16)a.x; v[1] = (__bf16)a.y; v[2] = (__bf16)a.z; v[3] = (__bf16)a.w;
      v[4] = (__bf16)b.x; v[5] = (__bf16)b.y; v[6] = (__bf16)b.z; v[7] = (__bf16)b.w;
      *(bf16x8*)(swA + (size_t)s * 8) = v;       // consecutive t -> contiguous 16B: coalesced
    }
  } else {
    // W part: per 64x64 tile, transpose via LDS then write fragment-ordered
    int bid = blockIdx.x - 1024;                 // 2048 blocks: 8 experts x 16 k0 x 16 n0
    int e = bid >> 8, r = bid & 255;
    int k0 = (r >> 4) * 64, n0 = (r & 15) * 64;
    const float* Wp = W + (size_t)e * KDIM * NDIM;
    int rr0 = t >> 4, c4 = t & 15;
#pragma unroll
    for (int p = 0; p < 4; ++p) {
      int kk = rr0 + p * 16;
      float4 v = *(const float4*)(Wp + (size_t)(k0 + kk) * NDIM + n0 + c4 * 4);
      Lt[(c4 * 4 + 0) * 72 + kk] = (__bf16)v.x;
      Lt[(c4 * 4 + 1) * 72 + kk] = (__bf16)v.y;
      Lt[(c4 * 4 + 2) * 72 + kk] = (__bf16)v.z;
      Lt[(c4 * 4 + 3) * 72 + kk] = (__bf16)v.w;
    }
    __syncthreads();
    // 64x64 tile = 4 n-panels x 2 kts x 64 lanes = 512 slots; 256 thr x 2
#pragma unroll
    for (int q = 0; q < 2; ++q) {
      int slot = q * 256 + t;
      int lane = slot & 63, grp = slot >> 6;     // grp 0..7
      int np = grp & 3, kt2 = grp >> 2;
      int nl = np * 16 + (lane & 15);
      int kl = kt2 * 32 + ((lane >> 4) << 3);
      bf16x8 v = *(const bf16x8*)(Lt + nl * 72 + kl);
      int panel = (n0 >> 4) + np;
      int ktg = (k0 >> 5) + kt2;
      size_t sg = (((size_t)e * 64 + panel) * 32 + ktg) * 64 + lane;
      *(bf16x8*)(swB + sg * 8) = v;              // coalesced 1KiB per wave
    }
  }
}

// ---------------- GEMM: zero-LDS, zero-barrier, 4-deep register pipeline ----------------
// m-tiles on the ABSOLUTE 128-row grid; boundary tiles straddling two experts get
// one block per overlapping expert; stores guarded to [lo,hi).
// Load->use distance = 3 mm-groups (~240+ cyc) > L2-hit latency (~200 cyc).
__global__ __launch_bounds__(256, 2) void moe_gemm_frag(
    const __bf16* __restrict__ swA, const __bf16* __restrict__ swB,
    const int* __restrict__ gs, const float* __restrict__ bias,
    float* __restrict__ out)
{
  int y = blockIdx.y;
  int e = 0, tile0 = 0, lo = 0, hi = 0, found = 0, off = 0;
#pragma unroll
  for (int i = 0; i < NEXP; ++i) {
    int g = gs[i];
    int first = off >> 7;
    int cnt = (g > 0) ? (((off + g - 1) >> 7) - first + 1) : 0;
    if (!found) {
      if (y < cnt) {
        found = 1; e = i; tile0 = (first + y) << 7;
        lo = max(tile0, off); hi = min(tile0 + 128, off + g);
      } else y -= cnt;
    }
    off += g;
  }
  if (!found) return;
  const int n0 = blockIdx.x * 128;

  const int t = threadIdx.x, lane = t & 63, wv = t >> 6;
  const int wm = wv & 1, wn = wv >> 1, lm = lane & 15, lg = lane >> 4;

  // fragment bases: frag i is +i*16384 elems (panel stride 32*64*8), kt is +kt*512
  const __bf16* aB = swA + (((size_t)((tile0 >> 4) + wm * 4) * 32) * 64 + lane) * 8;
  const __bf16* bB = swB + ((((size_t)e * 64 + (n0 >> 4) + wn * 4) * 32) * 64 + lane) * 8;

  f32x4 acc[4][4] = {};
  bf16x8 aF0[4], bF0[4], aF1[4], bF1[4], aF2[4], bF2[4], aF3[4], bF3[4];

  auto ld = [&](int kt, bf16x8* a, bf16x8* b) {
#pragma unroll
    for (int i = 0; i < 4; ++i) a[i] = *(const bf16x8*)(aB + (size_t)i * 16384 + kt * 512);
#pragma unroll
    for (int j = 0; j < 4; ++j) b[j] = *(const bf16x8*)(bB + (size_t)j * 16384 + kt * 512);
  };
  auto mm = [&](bf16x8* a, bf16x8* b) {
#pragma unroll
    for (int i = 0; i < 4; ++i)
#pragma unroll
      for (int j = 0; j < 4; ++j)
        acc[i][j] = __builtin_amdgcn_mfma_f32_16x16x32_bf16(a[i], b[j], acc[i][j], 0, 0, 0);
  };

  ld(0, aF0, bF0);
  ld(1, aF1, bF1);
  ld(2, aF2, bF2);
  ld(3, aF3, bF3);
  // main loop: 7 iters, no guards between ld and mm (kt = 0,4,...,24; loads kt+4..kt+7 <= 31)
#pragma unroll 1
  for (int kt = 0; kt < KDIM / 32 - 4; kt += 4) {
    mm(aF0, bF0); ld(kt + 4, aF0, bF0);
    mm(aF1, bF1); ld(kt + 5, aF1, bF1);
    mm(aF2, bF2); ld(kt + 6, aF2, bF2);
    mm(aF3, bF3); ld(kt + 7, aF3, bF3);
  }
  // tail: kt = 28..31, no more loads
  mm(aF0, bF0);
  mm(aF1, bF1);
  mm(aF2, bF2);
  mm(aF3, bF3);

  float bj[4];
#pragma unroll
  for (int j = 0; j < 4; ++j) bj[j] = bias[e * NDIM + n0 + wn * 64 + j * 16 + lm];
#pragma unroll
  for (int i = 0; i < 4; ++i)
#pragma unroll
    for (int r = 0; r < 4; ++r) {
      int rabs = tile0 + wm * 64 + i * 16 + lg * 4 + r;   // C/D: row = quad*4 + reg
      if (rabs >= lo && rabs < hi) {
#pragma unroll
        for (int j = 0; j < 4; ++j)
          out[(size_t)rabs * NDIM + n0 + wn * 64 + j * 16 + lm] = acc[i][j][r] + bj[j];
      }
    }
}

// ---------------- round-1 fallback (fp32 in-loop conversion) for small ws ----------------
#define LDA 40
__global__ __launch_bounds__(256) void moe_gemm_kernel(
    const float* __restrict__ x, const int* __restrict__ gs,
    const float* __restrict__ W, const float* __restrict__ bias,
    float* __restrict__ out)
{
  __shared__ __bf16 Al[128 * LDA];
  __shared__ __bf16 Bl[128 * LDA];
  const int e = blockIdx.z, mt = blockIdx.y, nt = blockIdx.x;
  int off = 0;
#pragma unroll
  for (int i = 0; i < NEXP; ++i) { int g = gs[i]; if (i < e) off += g; }
  const int ge = gs[e];
  const int m0 = mt * 128;
  if (m0 >= ge) return;
  const int rows = min(128, ge - m0);
  const int row0 = off + m0;
  const int n0 = nt * 128;
  const int t = threadIdx.x, lane = t & 63, wv = t >> 6;
  const int wm = wv & 1, wn = wv >> 1, lm = lane & 15, lg = lane >> 4;
  const int am = t >> 3, kq = t & 7, nb = t & 127, kh = t >> 7;
  float4 aReg[4]; float bReg[16];
  const float* Wp = W + (size_t)e * KDIM * NDIM + n0 + nb;
  auto load_tile = [&](int kt) {
#pragma unroll
    for (int p = 0; p < 4; ++p) {
      int r = am + 32 * p;
      if (r < rows) aReg[p] = *(const float4*)(x + (size_t)(row0 + r) * KDIM + kt * 32 + kq * 4);
      else aReg[p] = make_float4(0.f, 0.f, 0.f, 0.f);
    }
    const float* wp = Wp + (size_t)(kt * 32 + kh * 16) * NDIM;
#pragma unroll
    for (int j = 0; j < 16; ++j) bReg[j] = wp[(size_t)j * NDIM];
  };
  auto store_tile = [&]() {
#pragma unroll
    for (int p = 0; p < 4; ++p) {
      bf16x4 v;
      v[0] = (__bf16)aReg[p].x; v[1] = (__bf16)aReg[p].y;
      v[2] = (__bf16)aReg[p].z; v[3] = (__bf16)aReg[p].w;
      *(bf16x4*)(Al + (am + 32 * p) * LDA + kq * 4) = v;
    }
    bf16x8 b0, b1;
#pragma unroll
    for (int j = 0; j < 8; ++j) { b0[j] = (__bf16)bReg[j]; b1[j] = (__bf16)bReg[8 + j]; }
    *(bf16x8*)(Bl + nb * LDA + kh * 16) = b0;
    *(bf16x8*)(Bl + nb * LDA + kh * 16 + 8) = b1;
  };
  f32x4 acc[4][4] = {};
  load_tile(0);
#pragma unroll 1
  for (int kt = 0; kt < KDIM / 32; ++kt) {
    __syncthreads();
    store_tile();
    __syncthreads();
    if (kt + 1 < KDIM / 32) load_tile(kt + 1);
    bf16x8 af[4], bfr[4];
#pragma unroll
    for (int i = 0; i < 4; ++i)
      af[i] = *(const bf16x8*)(Al + (wm * 64 + i * 16 + lm) * LDA + lg * 8);
#pragma unroll
    for (int j = 0; j < 4; ++j)
      bfr[j] = *(const bf16x8*)(Bl + (wn * 64 + j * 16 + lm) * LDA + lg * 8);
#pragma unroll
    for (int i = 0; i < 4; ++i)
#pragma unroll
      for (int j = 0; j < 4; ++j)
        acc[i][j] = __builtin_amdgcn_mfma_f32_16x16x32_bf16(af[i], bfr[j], acc[i][j], 0, 0, 0);
  }
  float bj[4];
#pragma unroll
  for (int j = 0; j < 4; ++j) bj[j] = bias[e * NDIM + n0 + wn * 64 + j * 16 + lm];
#pragma unroll
  for (int i = 0; i < 4; ++i)
#pragma unroll
    for (int r = 0; r < 4; ++r) {
      int rr = wm * 64 + i * 16 + lg * 4 + r;
      if (rr < rows) {
#pragma unroll
        for (int j = 0; j < 4; ++j)
          out[(size_t)(row0 + rr) * NDIM + n0 + wn * 64 + j * 16 + lm] = acc[i][j][r] + bj[j];
      }
    }
}

extern "C" void kernel_launch(void* const* d_in, const int* in_sizes, int n_in,
                              void* d_out, int out_size, void* d_ws, size_t ws_size,
                              hipStream_t stream) {
  const float* x    = (const float*)d_in[0];
  const int*   gs   = (const int*)d_in[1];
  const float* W    = (const float*)d_in[2];
  const float* bias = (const float*)d_in[3];
  float*       out  = (float*)d_out;

  const size_t swA_bytes = (size_t)TTOK * KDIM * 2;
  const size_t swB_bytes = (size_t)NEXP * KDIM * NDIM * 2;
  if (ws_size >= swA_bytes + swB_bytes) {
    __bf16* swA = (__bf16*)d_ws;
    __bf16* swB = (__bf16*)((char*)d_ws + swA_bytes);
    prepass<<<dim3(1024 + 2048), 256, 0, stream>>>(x, W, swA, swB);
    // y: absolute 128-row m-tiles overlapped per expert (<=71) ; x: 8 n-tiles
    moe_gemm_frag<<<dim3(NDIM / 128, 72), 256, 0, stream>>>(swA, swB, gs, bias, out);
  } else {
    moe_gemm_kernel<<<dim3(NDIM / 128, TTOK / 128, NEXP), 256, 0, stream>>>(x, gs, W, bias, out);
  }
}

// Round 7
// 137.726 us; speedup vs baseline: 1.4689x; 1.0397x over previous
//
#include <hip/hip_runtime.h>
#include <hip/hip_bf16.h>

#define KDIM 1024
#define NDIM 1024
#define NEXP 8
#define TTOK 8192

typedef __bf16 bf16x8 __attribute__((ext_vector_type(8)));
typedef __bf16 bf16x4 __attribute__((ext_vector_type(4)));
typedef float  f32x4  __attribute__((ext_vector_type(4)));

__device__ __forceinline__ void gl2lds16(const void* g, void* l) {
  __builtin_amdgcn_global_load_lds(
      (const __attribute__((address_space(1))) void*)g,
      (__attribute__((address_space(3))) void*)l, 16, 0, 0);
}

// Fragment-swizzled layouts (16B per lane-slot):
//   swA slot(panel,kt,lane) = x[panel*16 + (lane&15)][kt*32 + (lane>>4)*8 .. +8]
//   swB slot(e,panel,kt,lane) = W[e][kt*32 + (lane>>4)*8 .. +8][panel*16 + (lane&15)]

// ---------------- prepass: build swA (x fp32->bf16) and swB (W transpose) ----------------
__global__ __launch_bounds__(256) void prepass(
    const float* __restrict__ x, const float* __restrict__ W,
    __bf16* __restrict__ swA, __bf16* __restrict__ swB)
{
  __shared__ __align__(16) __bf16 Lt[64 * 72];
  const int t = threadIdx.x;
  if (blockIdx.x < 1024) {
#pragma unroll
    for (int p = 0; p < 4; ++p) {
      int s = blockIdx.x * 1024 + p * 256 + t;
      int lane = s & 63, kt = (s >> 6) & 31, panel = s >> 11;
      int row = panel * 16 + (lane & 15);
      int k0 = kt * 32 + ((lane >> 4) << 3);
      const float* xp = x + (size_t)row * KDIM + k0;
      float4 a = *(const float4*)xp;
      float4 b = *(const float4*)(xp + 4);
      bf16x8 v;
      v[0] = (__bf16)a.x; v[1] = (__bf16)a.y; v[2] = (__bf16)a.z; v[3] = (__bf16)a.w;
      v[4] = (__bf16)b.x; v[5] = (__bf16)b.y; v[6] = (__bf16)b.z; v[7] = (__bf16)b.w;
      *(bf16x8*)(swA + (size_t)s * 8) = v;
    }
  } else {
    int bid = blockIdx.x - 1024;
    int e = bid >> 8, r = bid & 255;
    int k0 = (r >> 4) * 64, n0 = (r & 15) * 64;
    const float* Wp = W + (size_t)e * KDIM * NDIM;
    int rr0 = t >> 4, c4 = t & 15;
#pragma unroll
    for (int p = 0; p < 4; ++p) {
      int kk = rr0 + p * 16;
      float4 v = *(const float4*)(Wp + (size_t)(k0 + kk) * NDIM + n0 + c4 * 4);
      Lt[(c4 * 4 + 0) * 72 + kk] = (__bf16)v.x;
      Lt[(c4 * 4 + 1) * 72 + kk] = (__bf16)v.y;
      Lt[(c4 * 4 + 2) * 72 + kk] = (__bf16)v.z;
      Lt[(c4 * 4 + 3) * 72 + kk] = (__bf16)v.w;
    }
    __syncthreads();
#pragma unroll
    for (int q = 0; q < 2; ++q) {
      int slot = q * 256 + t;
      int lane = slot & 63, grp = slot >> 6;
      int np = grp & 3, kt2 = grp >> 2;
      int nl = np * 16 + (lane & 15);
      int kl = kt2 * 32 + ((lane >> 4) << 3);
      bf16x8 v = *(const bf16x8*)(Lt + nl * 72 + kl);
      int panel = (n0 >> 4) + np;
      int ktg = (k0 >> 5) + kt2;
      size_t sg = (((size_t)e * 64 + panel) * 32 + ktg) * 64 + lane;
      *(bf16x8*)(swB + sg * 8) = v;
    }
  }
}

// ---------------- GEMM: LDS broadcast, 3-stage pipeline, NO vmcnt(0) drain ----------------
// Each block stages its 128x128 tile's K-slice (A 8KB + B 8KB) ONCE into LDS via
// global_load_lds (halves fragment traffic vs direct loads: each byte read by 1
// wave instead of 2). Sync protocol: per-wave `s_waitcnt vmcnt(4)` (waits only
// the 2-iteration-old stage; prefetch stays in flight) + raw s_barrier.
// Safety: every wave waits its own contributions to slice kt, then rendezvous ->
// buffer kt complete. stage(kt+2) sits AFTER compute(kt): all waves passed
// barrier(kt) => finished reading buf[(kt-1)%3] == buf[(kt+2)%3]. No WAR race.
__global__ __launch_bounds__(256, 3) void moe_gemm_lds(
    const __bf16* __restrict__ swA, const __bf16* __restrict__ swB,
    const int* __restrict__ gs, const float* __restrict__ bias,
    float* __restrict__ out)
{
  __shared__ __align__(16) __bf16 buf[3][8192];   // 3 x 16 KB (A slots 0..511, B 512..1023)

  int y = blockIdx.y;
  int e = 0, tile0 = 0, lo = 0, hi = 0, found = 0, off = 0;
#pragma unroll
  for (int i = 0; i < NEXP; ++i) {
    int g = gs[i];
    int first = off >> 7;
    int cnt = (g > 0) ? (((off + g - 1) >> 7) - first + 1) : 0;
    if (!found) {
      if (y < cnt) {
        found = 1; e = i; tile0 = (first + y) << 7;
        lo = max(tile0, off); hi = min(tile0 + 128, off + g);
      } else y -= cnt;
    }
    off += g;
  }
  if (!found) return;                       // block-uniform: no barrier mismatch
  const int n0 = blockIdx.x * 128;

  const int t = threadIdx.x, lane = t & 63, wv = t >> 6;
  const int wm = wv & 1, wn = wv >> 1, lm = lane & 15, lg = lane >> 4;

  // staging sources: wave wv stages A panels {wv, 4+wv} and B panels {wv, 4+wv}
  // (panel stride = 32 kt * 512 elems = 16384; per-kt stride = 512 elems)
  const __bf16* gA0 = swA + (size_t)((tile0 >> 4) + wv) * 16384 + lane * 8;
  const __bf16* gA1 = swA + (size_t)((tile0 >> 4) + 4 + wv) * 16384 + lane * 8;
  const __bf16* gB0 = swB + (size_t)(e * 64 + (n0 >> 4) + wv) * 16384 + lane * 8;
  const __bf16* gB1 = swB + (size_t)(e * 64 + (n0 >> 4) + 4 + wv) * 16384 + lane * 8;

  auto stage = [&](int kt, int sb) {
    __bf16* l = &buf[sb][0];
    const int ko = kt * 512;
    gl2lds16(gA0 + ko, l + (size_t)(0 * 256 + wv * 64) * 8);   // A panel wv
    gl2lds16(gA1 + ko, l + (size_t)(1 * 256 + wv * 64) * 8);   // A panel 4+wv
    gl2lds16(gB0 + ko, l + (size_t)(2 * 256 + wv * 64) * 8);   // B panel wv
    gl2lds16(gB1 + ko, l + (size_t)(3 * 256 + wv * 64) * 8);   // B panel 4+wv
  };

  f32x4 acc[4][4] = {};
  auto compute = [&](const __bf16* l) {
    bf16x8 aF[4], bF[4];
#pragma unroll
    for (int i = 0; i < 4; ++i)
      aF[i] = *(const bf16x8*)(l + (size_t)((wm * 4 + i) * 64 + lane) * 8);
#pragma unroll
    for (int j = 0; j < 4; ++j)
      bF[j] = *(const bf16x8*)(l + 4096 + (size_t)((wn * 4 + j) * 64 + lane) * 8);
#pragma unroll
    for (int i = 0; i < 4; ++i)
#pragma unroll
      for (int j = 0; j < 4; ++j)
        acc[i][j] = __builtin_amdgcn_mfma_f32_16x16x32_bf16(aF[i], bF[j], acc[i][j], 0, 0, 0);
  };

  stage(0, 0);            // oldest 4 outstanding
  stage(1, 1);            // newest 4 outstanding
#pragma unroll 1
  for (int kt = 0; kt < KDIM / 32 - 1; ++kt) {
    // wait until <=4 outstanding: slice kt's 4 stages done; kt+1's stay in flight
    asm volatile("s_waitcnt vmcnt(4)" ::: "memory");
    asm volatile("s_barrier" ::: "memory");
    compute(&buf[kt % 3][0]);
    if (kt + 2 < KDIM / 32) stage(kt + 2, (kt + 2) % 3);
  }
  asm volatile("s_waitcnt vmcnt(0)" ::: "memory");   // final slice: nothing left in flight
  asm volatile("s_barrier" ::: "memory");
  compute(&buf[(KDIM / 32 - 1) % 3][0]);

  float bj[4];
#pragma unroll
  for (int j = 0; j < 4; ++j) bj[j] = bias[e * NDIM + n0 + wn * 64 + j * 16 + lm];
#pragma unroll
  for (int i = 0; i < 4; ++i)
#pragma unroll
    for (int r = 0; r < 4; ++r) {
      int rabs = tile0 + wm * 64 + i * 16 + lg * 4 + r;   // C/D: row = quad*4 + reg
      if (rabs >= lo && rabs < hi) {
#pragma unroll
        for (int j = 0; j < 4; ++j)
          out[(size_t)rabs * NDIM + n0 + wn * 64 + j * 16 + lm] = acc[i][j][r] + bj[j];
      }
    }
}

// ---------------- round-1 fallback (fp32 in-loop conversion) for small ws ----------------
#define LDA 40
__global__ __launch_bounds__(256) void moe_gemm_kernel(
    const float* __restrict__ x, const int* __restrict__ gs,
    const float* __restrict__ W, const float* __restrict__ bias,
    float* __restrict__ out)
{
  __shared__ __bf16 Al[128 * LDA];
  __shared__ __bf16 Bl[128 * LDA];
  const int e = blockIdx.z, mt = blockIdx.y, nt = blockIdx.x;
  int off = 0;
#pragma unroll
  for (int i = 0; i < NEXP; ++i) { int g = gs[i]; if (i < e) off += g; }
  const int ge = gs[e];
  const int m0 = mt * 128;
  if (m0 >= ge) return;
  const int rows = min(128, ge - m0);
  const int row0 = off + m0;
  const int n0 = nt * 128;
  const int t = threadIdx.x, lane = t & 63, wv = t >> 6;
  const int wm = wv & 1, wn = wv >> 1, lm = lane & 15, lg = lane >> 4;
  const int am = t >> 3, kq = t & 7, nb = t & 127, kh = t >> 7;
  float4 aReg[4]; float bReg[16];
  const float* Wp = W + (size_t)e * KDIM * NDIM + n0 + nb;
  auto load_tile = [&](int kt) {
#pragma unroll
    for (int p = 0; p < 4; ++p) {
      int r = am + 32 * p;
      if (r < rows) aReg[p] = *(const float4*)(x + (size_t)(row0 + r) * KDIM + kt * 32 + kq * 4);
      else aReg[p] = make_float4(0.f, 0.f, 0.f, 0.f);
    }
    const float* wp = Wp + (size_t)(kt * 32 + kh * 16) * NDIM;
#pragma unroll
    for (int j = 0; j < 16; ++j) bReg[j] = wp[(size_t)j * NDIM];
  };
  auto store_tile = [&]() {
#pragma unroll
    for (int p = 0; p < 4; ++p) {
      bf16x4 v;
      v[0] = (__bf16)aReg[p].x; v[1] = (__bf16)aReg[p].y;
      v[2] = (__bf16)aReg[p].z; v[3] = (__bf16)aReg[p].w;
      *(bf16x4*)(Al + (am + 32 * p) * LDA + kq * 4) = v;
    }
    bf16x8 b0, b1;
#pragma unroll
    for (int j = 0; j < 8; ++j) { b0[j] = (__bf16)bReg[j]; b1[j] = (__bf16)bReg[8 + j]; }
    *(bf16x8*)(Bl + nb * LDA + kh * 16) = b0;
    *(bf16x8*)(Bl + nb * LDA + kh * 16 + 8) = b1;
  };
  f32x4 acc[4][4] = {};
  load_tile(0);
#pragma unroll 1
  for (int kt = 0; kt < KDIM / 32; ++kt) {
    __syncthreads();
    store_tile();
    __syncthreads();
    if (kt + 1 < KDIM / 32) load_tile(kt + 1);
    bf16x8 af[4], bfr[4];
#pragma unroll
    for (int i = 0; i < 4; ++i)
      af[i] = *(const bf16x8*)(Al + (wm * 64 + i * 16 + lm) * LDA + lg * 8);
#pragma unroll
    for (int j = 0; j < 4; ++j)
      bfr[j] = *(const bf16x8*)(Bl + (wn * 64 + j * 16 + lm) * LDA + lg * 8);
#pragma unroll
    for (int i = 0; i < 4; ++i)
#pragma unroll
      for (int j = 0; j < 4; ++j)
        acc[i][j] = __builtin_amdgcn_mfma_f32_16x16x32_bf16(af[i], bfr[j], acc[i][j], 0, 0, 0);
  }
  float bj[4];
#pragma unroll
  for (int j = 0; j < 4; ++j) bj[j] = bias[e * NDIM + n0 + wn * 64 + j * 16 + lm];
#pragma unroll
  for (int i = 0; i < 4; ++i)
#pragma unroll
    for (int r = 0; r < 4; ++r) {
      int rr = wm * 64 + i * 16 + lg * 4 + r;
      if (rr < rows) {
#pragma unroll
        for (int j = 0; j < 4; ++j)
          out[(size_t)(row0 + rr) * NDIM + n0 + wn * 64 + j * 16 + lm] = acc[i][j][r] + bj[j];
      }
    }
}

extern "C" void kernel_launch(void* const* d_in, const int* in_sizes, int n_in,
                              void* d_out, int out_size, void* d_ws, size_t ws_size,
                              hipStream_t stream) {
  const float* x    = (const float*)d_in[0];
  const int*   gs   = (const int*)d_in[1];
  const float* W    = (const float*)d_in[2];
  const float* bias = (const float*)d_in[3];
  float*       out  = (float*)d_out;

  const size_t swA_bytes = (size_t)TTOK * KDIM * 2;
  const size_t swB_bytes = (size_t)NEXP * KDIM * NDIM * 2;
  if (ws_size >= swA_bytes + swB_bytes) {
    __bf16* swA = (__bf16*)d_ws;
    __bf16* swB = (__bf16*)((char*)d_ws + swA_bytes);
    prepass<<<dim3(1024 + 2048), 256, 0, stream>>>(x, W, swA, swB);
    // x = n-tile (8): linear id % 8 == n-tile -> each XCD keeps its B n-column
    // (8 experts x 256 KB = 2 MB) L2-resident.
    moe_gemm_lds<<<dim3(NDIM / 128, 72), 256, 0, stream>>>(swA, swB, gs, bias, out);
  } else {
    moe_gemm_kernel<<<dim3(NDIM / 128, TTOK / 128, NEXP), 256, 0, stream>>>(x, gs, W, bias, out);
  }
}